// Round 1
// baseline (468.919 us; speedup 1.0000x reference)
//
#include <hip/hip_runtime.h>

// SSIM loss, fully fused. Input: 2x (32,3,512,512) fp32. Output: scalar fp32.
// Tile: 32x32 outputs/block, 42x42 input halo tiles in LDS.
// d_ws: 96 floats of per-plane ssim sums.

#define TW 32
#define TH 32
#define IW 42          // TW + win - 1
#define IH 42
#define XS 43          // padded LDS row stride for input tiles (bank-conflict-free)
#define WIN 11
#define OUT_DIM 502    // 512 - 10 (VALID conv twice)
#define IMG 512
#define NPLANES 96

__global__ __launch_bounds__(256) void ssim_tile(const float* __restrict__ X,
                                                 const float* __restrict__ Y,
                                                 float* __restrict__ planeSums) {
    __shared__ float sX[IH * XS];          // 7224 B
    __shared__ float sY[IH * XS];          // 7224 B
    __shared__ float sH[5][IH][TW];        // 26880 B  (total ~41.3 KB -> 3 blocks/CU)

    const int tid = threadIdx.x;
    const int ox = blockIdx.x * TW;
    const int oy = blockIdx.y * TH;
    const int plane = blockIdx.z;
    const float* Xp = X + (size_t)plane * IMG * IMG;
    const float* Yp = Y + (size_t)plane * IMG * IMG;

    // Gaussian weights, computed in fp32 to match the numpy reference pipeline.
    float g[WIN];
    {
        float s = 0.f;
        #pragma unroll
        for (int k = 0; k < WIN; ++k) {
            float d = (float)k - 5.0f;
            g[k] = expf(-d * d / 4.5f);   // 2*sigma^2 = 4.5
            s += g[k];
        }
        float inv = 1.0f / s;
        #pragma unroll
        for (int k = 0; k < WIN; ++k) g[k] *= inv;
    }

    // ---- Load X/Y halo tiles into LDS (OOB -> 0; those feed only invalid outputs)
    for (int idx = tid; idx < IH * IW; idx += 256) {
        int r = idx / IW;
        int c = idx - r * IW;
        int gr = oy + r, gc = ox + c;
        float xv = 0.f, yv = 0.f;
        if (gr < IMG && gc < IMG) {
            xv = Xp[gr * IMG + gc];
            yv = Yp[gr * IMG + gc];
        }
        sX[r * XS + c] = xv;
        sY[r * XS + c] = yv;
    }
    __syncthreads();

    // ---- Stage A: horizontal 11-tap blur of the 5 product maps
    for (int pos = tid; pos < IH * TW; pos += 256) {
        int i = pos >> 5;
        int j = pos & 31;
        float hx = 0.f, hy = 0.f, hxx = 0.f, hyy = 0.f, hxy = 0.f;
        const float* rx = &sX[i * XS + j];
        const float* ry = &sY[i * XS + j];
        #pragma unroll
        for (int k = 0; k < WIN; ++k) {
            float w = g[k];
            float xv = rx[k];
            float yv = ry[k];
            hx  += w * xv;
            hy  += w * yv;
            hxx += w * (xv * xv);
            hyy += w * (yv * yv);
            hxy += w * (xv * yv);
        }
        sH[0][i][j] = hx;
        sH[1][i][j] = hy;
        sH[2][i][j] = hxx;
        sH[3][i][j] = hyy;
        sH[4][i][j] = hxy;
    }
    __syncthreads();

    // ---- Stage B: vertical blur + SSIM map + partial sum
    const float C1 = 0.0001f;   // (0.01*1)^2
    const float C2 = 0.0009f;   // (0.03*1)^2
    float local = 0.f;

    for (int pos = tid; pos < TH * TW; pos += 256) {
        int i = pos >> 5;
        int j = pos & 31;
        float mu1 = 0.f, mu2 = 0.f, sxx = 0.f, syy = 0.f, sxy = 0.f;
        #pragma unroll
        for (int k = 0; k < WIN; ++k) {
            float w = g[k];
            mu1 += w * sH[0][i + k][j];
            mu2 += w * sH[1][i + k][j];
            sxx += w * sH[2][i + k][j];
            syy += w * sH[3][i + k][j];
            sxy += w * sH[4][i + k][j];
        }
        float mu1sq = mu1 * mu1;
        float mu2sq = mu2 * mu2;
        float mu12  = mu1 * mu2;
        float s1  = sxx - mu1sq;
        float s2  = syy - mu2sq;
        float s12 = sxy - mu12;
        // ((2*mu12+C1)/(mu1sq+mu2sq+C1)) * ((2*s12+C2)/(s1+s2+C2)), one division
        float num = (2.f * mu12 + C1) * (2.f * s12 + C2);
        float den = (mu1sq + mu2sq + C1) * (s1 + s2 + C2);
        float ssim = num / den;
        if ((oy + i) < OUT_DIM && (ox + j) < OUT_DIM) local += ssim;
    }

    // ---- Block reduction -> one atomic per block
    #pragma unroll
    for (int off = 32; off > 0; off >>= 1)
        local += __shfl_down(local, off, 64);
    __shared__ float red[4];
    int wave = tid >> 6;
    int lane = tid & 63;
    if (lane == 0) red[wave] = local;
    __syncthreads();
    if (tid == 0) {
        float s = (red[0] + red[1]) + (red[2] + red[3]);
        atomicAdd(&planeSums[plane], s);
    }
}

__global__ __launch_bounds__(128) void ssim_finalize(const float* __restrict__ planeSums,
                                                     float* __restrict__ out) {
    const int tid = threadIdx.x;
    float v = 0.f;
    if (tid < NPLANES) {
        float m = planeSums[tid] * (1.0f / (float)(OUT_DIM * OUT_DIM));
        v = fmaxf(m, 0.f);   // nonnegative_ssim relu
    }
    #pragma unroll
    for (int off = 32; off > 0; off >>= 1)
        v += __shfl_down(v, off, 64);
    __shared__ float red[2];
    if ((tid & 63) == 0) red[tid >> 6] = v;
    __syncthreads();
    if (tid == 0) out[0] = 1.0f - (red[0] + red[1]) * (1.0f / (float)NPLANES);
}

extern "C" void kernel_launch(void* const* d_in, const int* in_sizes, int n_in,
                              void* d_out, int out_size, void* d_ws, size_t ws_size,
                              hipStream_t stream) {
    const float* X = (const float*)d_in[0];   // predictions
    const float* Y = (const float*)d_in[1];   // labels
    float* out = (float*)d_out;
    float* ws  = (float*)d_ws;                // 96 per-plane sums

    hipMemsetAsync(ws, 0, NPLANES * sizeof(float), stream);

    dim3 grid(IMG / TW, IMG / TH, NPLANES);   // 16 x 16 x 96
    ssim_tile<<<grid, 256, 0, stream>>>(X, Y, ws);
    ssim_finalize<<<1, 128, 0, stream>>>(ws, out);
}

// Round 2
// 369.958 us; speedup vs baseline: 1.2675x; 1.2675x over previous
//
#include <hip/hip_runtime.h>

// SSIM loss, fused. Inputs: 2x (32,3,512,512) fp32. Output: scalar fp32.
// Per block: 32x32 output tile. Stage A (horizontal 11-tap blur of the 5
// product maps) reads directly from global in 4-wide column strips (halo
// re-reads served by L1/L2); only the blurred maps live in LDS (26.9 KB ->
// 4+ blocks/CU). Stage B: each thread owns a 4-row vertical strip, reading
// 5x14 LDS values for 4 outputs (5x fewer LDS reads than tap-per-output).

#define TW 32
#define TH 32
#define IH 42          // TH + WIN - 1
#define WIN 11
#define OUT_DIM 502    // 512 - 10 (VALID conv twice)
#define IMG 512
#define NPLANES 96

__device__ __forceinline__ float4 ldg4(const float* p) { return *(const float4*)p; }

__global__ __launch_bounds__(256, 4) void ssim_tile(const float* __restrict__ X,
                                                    const float* __restrict__ Y,
                                                    float* __restrict__ planeSums) {
    // Gaussian(11, sigma=1.5) weights, normalized (matches numpy fp32 pipeline
    // to ~1e-7; threshold slack is 5 orders of magnitude).
    constexpr float G[WIN] = {0.00102838f, 0.00759875f, 0.03600077f, 0.10936071f,
                              0.21300553f, 0.26601172f, 0.21300553f, 0.10936071f,
                              0.03600077f, 0.00759875f, 0.00102838f};

    __shared__ float sH[5][IH][TW];   // 26880 B — sole LDS tile

    const int tid = threadIdx.x;
    const int ox = blockIdx.x * TW;
    const int oy = blockIdx.y * TH;
    const int plane = blockIdx.z;
    const float* Xp = X + (size_t)plane * IMG * IMG;
    const float* Yp = Y + (size_t)plane * IMG * IMG;

    // ---- Stage A: horizontal blur, 4-output strips, global -> LDS
    for (int s = tid; s < IH * (TW / 4); s += 256) {
        const int r = s >> 3;            // row in [0,42)
        const int j0 = (s & 7) << 2;     // first of 4 output cols
        const int gr = oy + r;
        float x[16], y[16];
        if (gr < IMG) {
            const float* px = Xp + gr * IMG + ox + j0;
            const float* py = Yp + gr * IMG + ox + j0;
            if (ox + j0 + 16 <= IMG) {
                #pragma unroll
                for (int q = 0; q < 4; ++q) {
                    *(float4*)&x[q * 4] = ldg4(px + q * 4);
                    *(float4*)&y[q * 4] = ldg4(py + q * 4);
                }
            } else {   // right-edge tiles only
                #pragma unroll
                for (int q = 0; q < 16; ++q) {
                    const int gc = ox + j0 + q;
                    x[q] = (gc < IMG) ? px[q] : 0.f;
                    y[q] = (gc < IMG) ? py[q] : 0.f;
                }
            }
        } else {       // below-image rows feed only invalid outputs
            #pragma unroll
            for (int q = 0; q < 16; ++q) { x[q] = 0.f; y[q] = 0.f; }
        }
        float h0[4] = {0,0,0,0}, h1[4] = {0,0,0,0}, h2[4] = {0,0,0,0},
              h3[4] = {0,0,0,0}, h4[4] = {0,0,0,0};
        #pragma unroll
        for (int k = 0; k < WIN; ++k) {
            const float w = G[k];
            #pragma unroll
            for (int c = 0; c < 4; ++c) {
                const float xv = x[k + c], yv = y[k + c];
                const float wx = w * xv, wy = w * yv;
                h0[c] += wx;
                h1[c] += wy;
                h2[c] += wx * xv;
                h3[c] += wy * yv;
                h4[c] += wx * yv;
            }
        }
        *(float4*)&sH[0][r][j0] = *(float4*)h0;
        *(float4*)&sH[1][r][j0] = *(float4*)h1;
        *(float4*)&sH[2][r][j0] = *(float4*)h2;
        *(float4*)&sH[3][r][j0] = *(float4*)h3;
        *(float4*)&sH[4][r][j0] = *(float4*)h4;
    }
    __syncthreads();

    // ---- Stage B: vertical blur over a 4-row strip per thread + SSIM
    const int j = tid & 31;
    const int i0 = (tid >> 5) << 2;      // 0,4,...,28
    float mu1[4] = {0,0,0,0}, mu2[4] = {0,0,0,0};
    float vxx[4] = {0,0,0,0}, vyy[4] = {0,0,0,0}, vxy[4] = {0,0,0,0};
    #pragma unroll
    for (int k = 0; k < 14; ++k) {       // 4 + WIN - 1 rows
        const float v0 = sH[0][i0 + k][j];
        const float v1 = sH[1][i0 + k][j];
        const float v2 = sH[2][i0 + k][j];
        const float v3 = sH[3][i0 + k][j];
        const float v4 = sH[4][i0 + k][j];
        #pragma unroll
        for (int i = 0; i < 4; ++i) {
            const int kk = k - i;
            if (kk >= 0 && kk < WIN) {
                const float w = G[kk];
                mu1[i] += w * v0;
                mu2[i] += w * v1;
                vxx[i] += w * v2;
                vyy[i] += w * v3;
                vxy[i] += w * v4;
            }
        }
    }

    const float C1 = 0.0001f;   // (0.01*1)^2
    const float C2 = 0.0009f;   // (0.03*1)^2
    float local = 0.f;
    #pragma unroll
    for (int i = 0; i < 4; ++i) {
        if ((oy + i0 + i) < OUT_DIM && (ox + j) < OUT_DIM) {
            const float m1 = mu1[i], m2 = mu2[i];
            const float m1sq = m1 * m1, m2sq = m2 * m2, m12 = m1 * m2;
            const float s1  = vxx[i] - m1sq;
            const float s2  = vyy[i] - m2sq;
            const float s12 = vxy[i] - m12;
            const float num = (2.f * m12 + C1) * (2.f * s12 + C2);
            const float den = (m1sq + m2sq + C1) * (s1 + s2 + C2);
            local += num * __builtin_amdgcn_rcpf(den);  // ~1ulp, irrelevant vs threshold
        }
    }

    // ---- Block reduction -> one atomic per block
    #pragma unroll
    for (int off = 32; off > 0; off >>= 1)
        local += __shfl_down(local, off, 64);
    __shared__ float red[4];
    const int wave = tid >> 6;
    const int lane = tid & 63;
    if (lane == 0) red[wave] = local;
    __syncthreads();
    if (tid == 0) {
        const float s = (red[0] + red[1]) + (red[2] + red[3]);
        atomicAdd(&planeSums[plane], s);
    }
}

__global__ __launch_bounds__(128) void ssim_finalize(const float* __restrict__ planeSums,
                                                     float* __restrict__ out) {
    const int tid = threadIdx.x;
    float v = 0.f;
    if (tid < NPLANES) {
        const float m = planeSums[tid] * (1.0f / (float)(OUT_DIM * OUT_DIM));
        v = fmaxf(m, 0.f);   // nonnegative_ssim relu
    }
    #pragma unroll
    for (int off = 32; off > 0; off >>= 1)
        v += __shfl_down(v, off, 64);
    __shared__ float red[2];
    if ((tid & 63) == 0) red[tid >> 6] = v;
    __syncthreads();
    if (tid == 0) out[0] = 1.0f - (red[0] + red[1]) * (1.0f / (float)NPLANES);
}

extern "C" void kernel_launch(void* const* d_in, const int* in_sizes, int n_in,
                              void* d_out, int out_size, void* d_ws, size_t ws_size,
                              hipStream_t stream) {
    const float* X = (const float*)d_in[0];   // predictions
    const float* Y = (const float*)d_in[1];   // labels
    float* out = (float*)d_out;
    float* ws  = (float*)d_ws;                // 96 per-plane sums

    hipMemsetAsync(ws, 0, NPLANES * sizeof(float), stream);

    dim3 grid(IMG / TW, IMG / TH, NPLANES);   // 16 x 16 x 96
    ssim_tile<<<grid, 256, 0, stream>>>(X, Y, ws);
    ssim_finalize<<<1, 128, 0, stream>>>(ws, out);
}